// Round 3
// baseline (127.124 us; speedup 1.0000x reference)
//
#include <hip/hip_runtime.h>
#include <hip/hip_bf16.h>
#include <math.h>

#define NROWS 8192
#define DIM   768
#define NKB   (DIM / 64)         // 12 k-blocks of 64
#define CHUNK (128 * 64 * 2)     // 16384 bytes per bf16 half-tile chunk
#define NT128 (NROWS / 128)      // 64 row-blocks of 128 (chunk granularity)
#define BM2   256
#define NT2   (NROWS / BM2)      // 32 tile-blocks of 256
#define NKT   NKB                // 12 K-tiles of 64

typedef __attribute__((ext_vector_type(4))) float  f32x4;
typedef __attribute__((ext_vector_type(8))) __bf16 bf16x8;
typedef __attribute__((ext_vector_type(4))) __bf16 bf16x4;

__device__ __forceinline__ void gload_lds16(const void* g, void* l) {
  __builtin_amdgcn_global_load_lds(
      (const __attribute__((address_space(1))) void*)g,
      (__attribute__((address_space(3))) void*)l, 16, 0, 0);
}

// ---------------------------------------------------------------------------
// Kernel A: fused convert+prep. One wave per row: f32 -> sq-norm (exact) AND
// bf16 conversion into 128x64 chunk layout with LDS swizzle PRE-APPLIED:
//   chunk(rb, kb) holds rows rb*128.., cols kb*64..; element (r,c) at byte
//   (r*128 + c*2) ^ ((r&7)<<4).
// ---------------------------------------------------------------------------
__global__ __launch_bounds__(256) void koleo_convert(const float* __restrict__ X,
                                                     float* __restrict__ sq,
                                                     unsigned int* __restrict__ minbits,
                                                     char* __restrict__ xbf) {
  const int row  = blockIdx.x * 4 + (threadIdx.x >> 6);
  const int lane = threadIdx.x & 63;
  const int rb = row >> 7, r = row & 127;
  const float* xr = X + (size_t)row * DIM;
  float s = 0.f;
#pragma unroll
  for (int i = 0; i < 3; ++i) {            // 768 = 3 * 64 lanes * 4 floats
    const int c0 = lane * 4 + i * 256;
    f32x4 v = *(const f32x4*)(xr + c0);
    s += v.x * v.x + v.y * v.y + v.z * v.z + v.w * v.w;
    bf16x4 h;
    h[0] = (__bf16)v.x; h[1] = (__bf16)v.y; h[2] = (__bf16)v.z; h[3] = (__bf16)v.w;
    const int kb = c0 >> 6;
    const int c  = c0 & 63;
    const int off = (r * 128 + c * 2) ^ ((r & 7) << 4);
    *(bf16x4*)(xbf + (size_t)(rb * NKB + kb) * CHUNK + off) = h;
  }
#pragma unroll
  for (int m = 32; m >= 1; m >>= 1) s += __shfl_xor(s, m, 64);
  if (lane == 0) {
    sq[row]      = s;
    minbits[row] = 0x7F800000u;            // +inf
  }
}

// ---------------------------------------------------------------------------
// Kernel B: 256x256 upper-triangular Gram tiles, 8 waves (2M x 4N),
// phase-split pipelined schedule (T3+T4 style): 4 phases per K-tile, one
// half-tile (16KB, 2x global_load_lds) prefetched per phase into the other
// double-buffer, single vmcnt(0) per K-tile AFTER the last MFMA phase.
// LDS: 2 dbuf x [A0,A1,B0,B1] x 16KB = 128KB (dynamic).
// ---------------------------------------------------------------------------
#define LDA_Q(qm)                                                             \
  _Pragma("unroll") for (int mm = 0; mm < 4; ++mm) {                          \
    const int ra = wm * 128 + (qm) * 64 + mm * 16 + (lane & 15);              \
    const int ha = ra >> 7, rr = ra & 127;                                    \
    _Pragma("unroll") for (int ks = 0; ks < 2; ++ks)                          \
      aF[mm][ks] = *(const bf16x8*)(buf + ha * 16384 +                        \
          ((rr * 128 + ks * 64 + ((lane >> 4) * 16)) ^ ((rr & 7) << 4)));     \
  }

#define LDB_Q(qn)                                                             \
  _Pragma("unroll") for (int nn = 0; nn < 2; ++nn) {                          \
    const int rb2 = wn * 64 + (qn) * 32 + nn * 16 + (lane & 15);              \
    const int hb = rb2 >> 7, rr = rb2 & 127;                                  \
    _Pragma("unroll") for (int ks = 0; ks < 2; ++ks)                          \
      bF[qn][nn][ks] = *(const bf16x8*)(buf + 32768 + hb * 16384 +            \
          ((rr * 128 + ks * 64 + ((lane >> 4) * 16)) ^ ((rr & 7) << 4)));     \
  }

#define MFMA_Q(qm, qn)                                                        \
  __builtin_amdgcn_s_setprio(1);                                              \
  _Pragma("unroll") for (int mm = 0; mm < 4; ++mm)                            \
  _Pragma("unroll") for (int nn = 0; nn < 2; ++nn)                            \
  _Pragma("unroll") for (int ks = 0; ks < 2; ++ks)                            \
    acc[(qm) * 4 + mm][(qn) * 2 + nn] = __builtin_amdgcn_mfma_f32_16x16x32_bf16( \
        aF[mm][ks], bF[qn][nn][ks], acc[(qm) * 4 + mm][(qn) * 2 + nn], 0, 0, 0); \
  __builtin_amdgcn_s_setprio(0);

#define STAGE_SLOT(s)                                                         \
  if (more) {                                                                 \
    const char* src = xbf + ((size_t)rbs[s] * NKB + (t + 1)) * CHUNK          \
                      + wave * 1024 + lane * 16;                              \
    char* dst = buf2 + (s) * 16384 + wave * 1024;                             \
    gload_lds16(src,        dst);                                             \
    gload_lds16(src + 8192, dst + 8192);                                      \
  }

__global__ __launch_bounds__(512, 2) void koleo_tile8(const char* __restrict__ xbf,
                                                      const float* __restrict__ sq,
                                                      unsigned int* __restrict__ minbits) {
  extern __shared__ char lds[];            // 131072 bytes

  // XCD-bijective swizzle (528 = 8 * 66), then upper-triangular map
  const int raw = blockIdx.x;
  int b = (raw & 7) * 66 + (raw >> 3);
  int rem = b, ti = 0, rowlen = NT2;
  while (rem >= rowlen) { rem -= rowlen; ++ti; --rowlen; }
  const int tj = ti + rem;
  const int i0 = ti * BM2, j0 = tj * BM2;

  const int tid  = threadIdx.x;
  const int lane = tid & 63;
  const int wave = tid >> 6;               // 0..7
  const int wm   = wave >> 2;              // 0..1 (row half: 128 rows)
  const int wn   = wave & 3;               // 0..3 (col quarter: 64 cols)

  const int rbs[4] = { 2 * ti, 2 * ti + 1, 2 * tj, 2 * tj + 1 };

  f32x4 acc[8][4] = {};
  bf16x8 aF[4][2];                         // current qm's A fragments
  bf16x8 bF[2][2][2];                      // [qn][nn][ks] B fragments (both qn held)

  // ---- prologue: stage K-tile 0 into dbuf 0, full drain once -------------
#pragma unroll
  for (int s = 0; s < 4; ++s) {
    const char* src = xbf + ((size_t)rbs[s] * NKB + 0) * CHUNK + wave * 1024 + lane * 16;
    char* dst = lds + s * 16384 + wave * 1024;
    gload_lds16(src,        dst);
    gload_lds16(src + 8192, dst + 8192);
  }
  asm volatile("s_waitcnt vmcnt(0)" ::: "memory");
  __builtin_amdgcn_s_barrier();

  // ---- main K-loop: 4 phases per K-tile ----------------------------------
  for (int t = 0; t < NKT; ++t) {
    char* buf  = lds + (t & 1) * 65536;
    char* buf2 = lds + ((t + 1) & 1) * 65536;
    const bool more = (t + 1 < NKT);

    // phase 0: A(qm=0) + B(qn=0) reads; prefetch half A0(t+1)
    LDA_Q(0); LDB_Q(0); STAGE_SLOT(0);
    __builtin_amdgcn_s_barrier();
    MFMA_Q(0, 0);
    __builtin_amdgcn_s_barrier();

    // phase 1: B(qn=1) reads; prefetch A1(t+1)
    LDB_Q(1); STAGE_SLOT(1);
    __builtin_amdgcn_s_barrier();
    MFMA_Q(0, 1);
    __builtin_amdgcn_s_barrier();

    // phase 2: A(qm=1) reads; prefetch B0(t+1)
    LDA_Q(1); STAGE_SLOT(2);
    __builtin_amdgcn_s_barrier();
    MFMA_Q(1, 0);
    __builtin_amdgcn_s_barrier();

    // phase 3: no reads; prefetch B1(t+1); drain AFTER the MFMAs
    STAGE_SLOT(3);
    __builtin_amdgcn_s_barrier();
    MFMA_Q(1, 1);
    if (more) asm volatile("s_waitcnt vmcnt(0)" ::: "memory");
    __builtin_amdgcn_s_barrier();
  }

  // ---- epilogue: d2, diagonal mask, row-min + col-min, atomicMin ----------
  // C/D layout (m89): col = lane&15, row = (lane>>4)*4 + reg
  const int cg = lane >> 4;
  const int cl = lane & 15;
  float sqj[4], colmin[4];
#pragma unroll
  for (int n = 0; n < 4; ++n) {
    sqj[n]    = sq[j0 + wn * 64 + n * 16 + cl];
    colmin[n] = INFINITY;
  }
#pragma unroll
  for (int m = 0; m < 8; ++m) {
#pragma unroll
    for (int r = 0; r < 4; ++r) {
      const int gi = i0 + wm * 128 + m * 16 + cg * 4 + r;
      const float si = sq[gi];
      float rowmin = INFINITY;
#pragma unroll
      for (int n = 0; n < 4; ++n) {
        const int gj = j0 + wn * 64 + n * 16 + cl;
        float d2 = si + sqj[n] - 2.0f * acc[m][n][r];
        d2 = fmaxf(d2, 0.0f);
        if (gi == gj) d2 = INFINITY;
        rowmin    = fminf(rowmin, d2);
        colmin[n] = fminf(colmin[n], d2);
      }
      rowmin = fminf(rowmin, __shfl_xor(rowmin, 1, 64));
      rowmin = fminf(rowmin, __shfl_xor(rowmin, 2, 64));
      rowmin = fminf(rowmin, __shfl_xor(rowmin, 4, 64));
      rowmin = fminf(rowmin, __shfl_xor(rowmin, 8, 64));
      if (cl == 0)
        atomicMin(minbits + gi, __float_as_uint(rowmin));
    }
  }
  if (ti != tj) {
#pragma unroll
    for (int n = 0; n < 4; ++n) {
      float cm = colmin[n];
      cm = fminf(cm, __shfl_xor(cm, 16, 64));
      cm = fminf(cm, __shfl_xor(cm, 32, 64));
      if (cg == 0)
        atomicMin(minbits + j0 + wn * 64 + n * 16 + cl, __float_as_uint(cm));
    }
  }
}

// ---------------------------------------------------------------------------
// Fallback (ws too small): f32 load + in-loop cvt staging, 128^2 tiles.
// ---------------------------------------------------------------------------
__global__ __launch_bounds__(256) void koleo_prep_fb(const float* __restrict__ X,
                                                     float* __restrict__ sq,
                                                     unsigned int* __restrict__ minbits) {
  const int row  = blockIdx.x * 4 + (threadIdx.x >> 6);
  const int lane = threadIdx.x & 63;
  const float* xr = X + (size_t)row * DIM;
  float s = 0.f;
#pragma unroll
  for (int i = 0; i < 3; ++i) {
    f32x4 v = *(const f32x4*)(xr + lane * 4 + i * 256);
    s += v.x * v.x + v.y * v.y + v.z * v.z + v.w * v.w;
  }
#pragma unroll
  for (int m = 32; m >= 1; m >>= 1) s += __shfl_xor(s, m, 64);
  if (lane == 0) { sq[row] = s; minbits[row] = 0x7F800000u; }
}

__global__ __launch_bounds__(256) void koleo_tile_fb(const float* __restrict__ X,
                                                     const float* __restrict__ sq,
                                                     unsigned int* __restrict__ minbits) {
  __shared__ __align__(16) char sA[CHUNK];
  __shared__ __align__(16) char sB[CHUNK];
  int rem = blockIdx.x, ti = 0, rowlen = NT128;
  while (rem >= rowlen) { rem -= rowlen; ++ti; --rowlen; }
  const int tj = ti + rem;
  const int i0 = ti * 128, j0 = tj * 128;
  const int tid = threadIdx.x, lane = tid & 63, wave = tid >> 6;
  const int wr = wave >> 1, wc = wave & 1;
  f32x4 acc[4][4] = {};
  for (int k0 = 0; k0 < DIM; k0 += 64) {
    __syncthreads();
#pragma unroll
    for (int it = 0; it < 8; ++it) {
      const int idx = tid + it * 256;
      const int r = idx >> 4, c4 = idx & 15;
      f32x4 va = *(const f32x4*)(X + (size_t)(i0 + r) * DIM + k0 + c4 * 4);
      f32x4 vb = *(const f32x4*)(X + (size_t)(j0 + r) * DIM + k0 + c4 * 4);
      bf16x4 ha, hb;
      ha[0] = (__bf16)va.x; ha[1] = (__bf16)va.y; ha[2] = (__bf16)va.z; ha[3] = (__bf16)va.w;
      hb[0] = (__bf16)vb.x; hb[1] = (__bf16)vb.y; hb[2] = (__bf16)vb.z; hb[3] = (__bf16)vb.w;
      int off = (r * 128 + c4 * 8) ^ ((r & 7) << 4);
      *(bf16x4*)(sA + off) = ha;
      *(bf16x4*)(sB + off) = hb;
    }
    __syncthreads();
#pragma unroll
    for (int ks = 0; ks < 2; ++ks) {
      bf16x8 af[4], bfr[4];
#pragma unroll
      for (int m = 0; m < 4; ++m) {
        const int ra = wr * 64 + m * 16 + (lane & 15);
        af[m]  = *(const bf16x8*)(sA + ((ra * 128 + ks * 64 + (lane >> 4) * 16) ^ ((ra & 7) << 4)));
        const int rb2 = wc * 64 + m * 16 + (lane & 15);
        bfr[m] = *(const bf16x8*)(sB + ((rb2 * 128 + ks * 64 + (lane >> 4) * 16) ^ ((rb2 & 7) << 4)));
      }
#pragma unroll
      for (int m = 0; m < 4; ++m)
#pragma unroll
        for (int n = 0; n < 4; ++n)
          acc[m][n] = __builtin_amdgcn_mfma_f32_16x16x32_bf16(af[m], bfr[n], acc[m][n], 0, 0, 0);
    }
  }
  const int cg = lane >> 4, cl = lane & 15;
  float sqj[4], colmin[4];
#pragma unroll
  for (int n = 0; n < 4; ++n) { sqj[n] = sq[j0 + wc * 64 + n * 16 + cl]; colmin[n] = INFINITY; }
#pragma unroll
  for (int m = 0; m < 4; ++m) {
#pragma unroll
    for (int r = 0; r < 4; ++r) {
      const int gi = i0 + wr * 64 + m * 16 + cg * 4 + r;
      const float si = sq[gi];
      float rowmin = INFINITY;
#pragma unroll
      for (int n = 0; n < 4; ++n) {
        const int gj = j0 + wc * 64 + n * 16 + cl;
        float d2 = si + sqj[n] - 2.0f * acc[m][n][r];
        d2 = fmaxf(d2, 0.0f);
        if (gi == gj) d2 = INFINITY;
        rowmin = fminf(rowmin, d2);
        colmin[n] = fminf(colmin[n], d2);
      }
      rowmin = fminf(rowmin, __shfl_xor(rowmin, 1, 64));
      rowmin = fminf(rowmin, __shfl_xor(rowmin, 2, 64));
      rowmin = fminf(rowmin, __shfl_xor(rowmin, 4, 64));
      rowmin = fminf(rowmin, __shfl_xor(rowmin, 8, 64));
      if (cl == 0) atomicMin(minbits + gi, __float_as_uint(rowmin));
    }
  }
  if (ti != tj) {
#pragma unroll
    for (int n = 0; n < 4; ++n) {
      float cm = colmin[n];
      cm = fminf(cm, __shfl_xor(cm, 16, 64));
      cm = fminf(cm, __shfl_xor(cm, 32, 64));
      if (cg == 0) atomicMin(minbits + j0 + wc * 64 + n * 16 + cl, __float_as_uint(cm));
    }
  }
}

// ---------------------------------------------------------------------------
// Final: loss = -mean(log(sqrt(min_d2) + eps)), single block
// ---------------------------------------------------------------------------
__global__ __launch_bounds__(1024) void koleo_final(const unsigned int* __restrict__ minbits,
                                                    float* __restrict__ out) {
  __shared__ float wsum[16];
  float s = 0.f;
  for (int i = threadIdx.x; i < NROWS; i += 1024) {
    float d2 = __uint_as_float(minbits[i]);
    s += logf(sqrtf(d2) + 1e-8f);
  }
#pragma unroll
  for (int m = 32; m >= 1; m >>= 1) s += __shfl_xor(s, m, 64);
  const int wv = threadIdx.x >> 6, ln = threadIdx.x & 63;
  if (ln == 0) wsum[wv] = s;
  __syncthreads();
  if (wv == 0) {
    float t = (ln < 16) ? wsum[ln] : 0.f;
#pragma unroll
    for (int m = 8; m >= 1; m >>= 1) t += __shfl_xor(t, m, 64);
    if (ln == 0) out[0] = -t / (float)NROWS;
  }
}

// ---------------------------------------------------------------------------
extern "C" void kernel_launch(void* const* d_in, const int* in_sizes, int n_in,
                              void* d_out, int out_size, void* d_ws, size_t ws_size,
                              hipStream_t stream) {
  const float* X = (const float*)d_in[0];
  float* out = (float*)d_out;
  unsigned int* minbits = (unsigned int*)d_ws;                       // 32 KB
  float* sq = (float*)((char*)d_ws + NROWS * sizeof(unsigned int));  // 32 KB
  char* xbf = (char*)d_ws + 65536;                                   // 12.58 MB

  const size_t need = 65536 + (size_t)NT128 * NKB * CHUNK;
  if (ws_size >= need) {
    koleo_convert<<<NROWS / 4, 256, 0, stream>>>(X, sq, minbits, xbf);
    koleo_tile8<<<NT2 * (NT2 + 1) / 2, 512, 131072, stream>>>(xbf, sq, minbits);
  } else {
    koleo_prep_fb<<<NROWS / 4, 256, 0, stream>>>(X, sq, minbits);
    koleo_tile_fb<<<NT128 * (NT128 + 1) / 2, 256, 0, stream>>>(X, sq, minbits);
  }
  koleo_final<<<1, 1024, 0, stream>>>(minbits, out);
}

// Round 4
// 124.332 us; speedup vs baseline: 1.0225x; 1.0225x over previous
//
#include <hip/hip_runtime.h>
#include <hip/hip_bf16.h>
#include <math.h>

#define NROWS 8192
#define DIM   768
#define NKB   (DIM / 64)         // 12 k-blocks of 64
#define CHUNK (128 * 64 * 2)     // 16384 bytes per bf16 chunk (128 rows x 64 cols)
#define NT128 (NROWS / 128)      // 64 row-blocks
#define NTILES (NT128 * (NT128 + 1) / 2)   // 2080 upper-tri tiles
#define XCHUNK (NTILES / 8)      // 260 — exact, bijective XCD swizzle

typedef __attribute__((ext_vector_type(4))) float  f32x4;
typedef __attribute__((ext_vector_type(8))) __bf16 bf16x8;
typedef __attribute__((ext_vector_type(4))) __bf16 bf16x4;

__device__ __forceinline__ void gload_lds16(const void* g, void* l) {
  __builtin_amdgcn_global_load_lds(
      (const __attribute__((address_space(1))) void*)g,
      (__attribute__((address_space(3))) void*)l, 16, 0, 0);
}

// ---------------------------------------------------------------------------
// Kernel A: fused convert+prep. One wave per row: f32 -> sq-norm (exact) AND
// bf16 conversion into 128x64 chunk layout with LDS swizzle PRE-APPLIED:
//   chunk(rb, kb) holds rows rb*128.., cols kb*64..; element (r,c) at byte
//   (r*128 + c*2) ^ ((r&7)<<4).
// ---------------------------------------------------------------------------
__global__ __launch_bounds__(256) void koleo_convert(const float* __restrict__ X,
                                                     float* __restrict__ sq,
                                                     unsigned int* __restrict__ minbits,
                                                     char* __restrict__ xbf) {
  const int row  = blockIdx.x * 4 + (threadIdx.x >> 6);
  const int lane = threadIdx.x & 63;
  const int rb = row >> 7, r = row & 127;
  const float* xr = X + (size_t)row * DIM;
  float s = 0.f;
#pragma unroll
  for (int i = 0; i < 3; ++i) {            // 768 = 3 * 64 lanes * 4 floats
    const int c0 = lane * 4 + i * 256;
    f32x4 v = *(const f32x4*)(xr + c0);
    s += v.x * v.x + v.y * v.y + v.z * v.z + v.w * v.w;
    bf16x4 h;
    h[0] = (__bf16)v.x; h[1] = (__bf16)v.y; h[2] = (__bf16)v.z; h[3] = (__bf16)v.w;
    const int kb = c0 >> 6;
    const int c  = c0 & 63;
    const int off = (r * 128 + c * 2) ^ ((r & 7) << 4);
    *(bf16x4*)(xbf + (size_t)(rb * NKB + kb) * CHUNK + off) = h;
  }
#pragma unroll
  for (int m = 32; m >= 1; m >>= 1) s += __shfl_xor(s, m, 64);
  if (lane == 0) {
    sq[row]      = s;
    minbits[row] = 0x7F800000u;            // +inf
  }
}

// ---------------------------------------------------------------------------
// Kernel B: 128x128 upper-triangular Gram tiles, 4 waves (2x2), 2-PHASE
// double-buffered schedule: per K-step issue next tile's 8 global_load_lds
// into the other buffer FIRST, then 16 ds_read_b128 + 32 MFMA on current
// buffer, then vmcnt(0) (loads had the whole compute to land) + ONE barrier.
// LDS: 2 x (A 16KB + B 16KB) = 64 KB dynamic -> 2 blocks/CU.
// ---------------------------------------------------------------------------
__global__ __launch_bounds__(256) void koleo_tile2(const char* __restrict__ xbf,
                                                   const float* __restrict__ sq,
                                                   unsigned int* __restrict__ minbits) {
  extern __shared__ char lds[];            // 65536 bytes

  // bijective XCD swizzle (2080 = 8 * 260), then upper-triangular map
  const int raw = blockIdx.x;
  int b = (raw & 7) * XCHUNK + (raw >> 3);
  int rem = b, ti = 0, rowlen = NT128;
  while (rem >= rowlen) { rem -= rowlen; ++ti; --rowlen; }
  const int tj = ti + rem;
  const int i0 = ti * 128, j0 = tj * 128;

  const int tid  = threadIdx.x;
  const int lane = tid & 63;
  const int wave = tid >> 6;               // 0..3
  const int wr   = wave >> 1;              // row half
  const int wc   = wave & 1;               // col half

  const char* baseA = xbf + (size_t)ti * NKB * CHUNK + wave * 4096 + lane * 16;
  const char* baseB = xbf + (size_t)tj * NKB * CHUNK + wave * 4096 + lane * 16;

  f32x4 acc[4][4] = {};

  // ---- prologue: stage K-tile 0 into buffer 0 ----------------------------
#pragma unroll
  for (int q = 0; q < 4; ++q) {
    gload_lds16(baseA + q * 1024, lds +         wave * 4096 + q * 1024);
    gload_lds16(baseB + q * 1024, lds + 16384 + wave * 4096 + q * 1024);
  }
  asm volatile("s_waitcnt vmcnt(0)" ::: "memory");
  __builtin_amdgcn_s_barrier();

  // ---- main K-loop: one barrier per K-step -------------------------------
  for (int t = 0; t < NKB; ++t) {
    char* buf  = lds + (t & 1) * 32768;
    char* nbuf = lds + ((t + 1) & 1) * 32768;
    const bool more = (t + 1 < NKB);

    if (more) {                            // issue next-tile staging FIRST
      const char* sA = baseA + (size_t)(t + 1) * CHUNK;
      const char* sB = baseB + (size_t)(t + 1) * CHUNK;
#pragma unroll
      for (int q = 0; q < 4; ++q) {
        gload_lds16(sA + q * 1024, nbuf +         wave * 4096 + q * 1024);
        gload_lds16(sB + q * 1024, nbuf + 16384 + wave * 4096 + q * 1024);
      }
    }

#pragma unroll
    for (int ks = 0; ks < 2; ++ks) {       // two K=32 steps per K-tile
      bf16x8 af[4], bfr[4];
#pragma unroll
      for (int m = 0; m < 4; ++m) {
        const int ra = wr * 64 + m * 16 + (lane & 15);
        af[m]  = *(const bf16x8*)(buf + ((ra * 128 + ks * 64 + (lane >> 4) * 16) ^ ((ra & 7) << 4)));
        const int rb2 = wc * 64 + m * 16 + (lane & 15);
        bfr[m] = *(const bf16x8*)(buf + 16384 + ((rb2 * 128 + ks * 64 + (lane >> 4) * 16) ^ ((rb2 & 7) << 4)));
      }
#pragma unroll
      for (int m = 0; m < 4; ++m)
#pragma unroll
        for (int n = 0; n < 4; ++n)
          acc[m][n] = __builtin_amdgcn_mfma_f32_16x16x32_bf16(af[m], bfr[n], acc[m][n], 0, 0, 0);
    }

    if (more) asm volatile("s_waitcnt vmcnt(0)" ::: "memory");
    __builtin_amdgcn_s_barrier();
  }

  // ---- epilogue: d2, diagonal mask, row-min + col-min, atomicMin ----------
  // C/D layout (m89): col = lane&15, row = (lane>>4)*4 + reg
  const int cg = lane >> 4;
  const int cl = lane & 15;
  float sqj[4], colmin[4];
#pragma unroll
  for (int n = 0; n < 4; ++n) {
    sqj[n]    = sq[j0 + wc * 64 + n * 16 + cl];
    colmin[n] = INFINITY;
  }
#pragma unroll
  for (int m = 0; m < 4; ++m) {
#pragma unroll
    for (int r = 0; r < 4; ++r) {
      const int gi = i0 + wr * 64 + m * 16 + cg * 4 + r;
      const float si = sq[gi];
      float rowmin = INFINITY;
#pragma unroll
      for (int n = 0; n < 4; ++n) {
        const int gj = j0 + wc * 64 + n * 16 + cl;
        float d2 = si + sqj[n] - 2.0f * acc[m][n][r];
        d2 = fmaxf(d2, 0.0f);
        if (gi == gj) d2 = INFINITY;
        rowmin    = fminf(rowmin, d2);
        colmin[n] = fminf(colmin[n], d2);
      }
      rowmin = fminf(rowmin, __shfl_xor(rowmin, 1, 64));
      rowmin = fminf(rowmin, __shfl_xor(rowmin, 2, 64));
      rowmin = fminf(rowmin, __shfl_xor(rowmin, 4, 64));
      rowmin = fminf(rowmin, __shfl_xor(rowmin, 8, 64));
      if (cl == 0)
        atomicMin(minbits + gi, __float_as_uint(rowmin));
    }
  }
  if (ti != tj) {
#pragma unroll
    for (int n = 0; n < 4; ++n) {
      float cm = colmin[n];
      cm = fminf(cm, __shfl_xor(cm, 16, 64));
      cm = fminf(cm, __shfl_xor(cm, 32, 64));
      if (cg == 0)
        atomicMin(minbits + j0 + wc * 64 + n * 16 + cl, __float_as_uint(cm));
    }
  }
}

// ---------------------------------------------------------------------------
// Fallback (ws too small): f32 load + in-loop cvt staging, 128^2 tiles.
// ---------------------------------------------------------------------------
__global__ __launch_bounds__(256) void koleo_prep_fb(const float* __restrict__ X,
                                                     float* __restrict__ sq,
                                                     unsigned int* __restrict__ minbits) {
  const int row  = blockIdx.x * 4 + (threadIdx.x >> 6);
  const int lane = threadIdx.x & 63;
  const float* xr = X + (size_t)row * DIM;
  float s = 0.f;
#pragma unroll
  for (int i = 0; i < 3; ++i) {
    f32x4 v = *(const f32x4*)(xr + lane * 4 + i * 256);
    s += v.x * v.x + v.y * v.y + v.z * v.z + v.w * v.w;
  }
#pragma unroll
  for (int m = 32; m >= 1; m >>= 1) s += __shfl_xor(s, m, 64);
  if (lane == 0) { sq[row] = s; minbits[row] = 0x7F800000u; }
}

__global__ __launch_bounds__(256) void koleo_tile_fb(const float* __restrict__ X,
                                                     const float* __restrict__ sq,
                                                     unsigned int* __restrict__ minbits) {
  __shared__ __align__(16) char sA[CHUNK];
  __shared__ __align__(16) char sB[CHUNK];
  int rem = blockIdx.x, ti = 0, rowlen = NT128;
  while (rem >= rowlen) { rem -= rowlen; ++ti; --rowlen; }
  const int tj = ti + rem;
  const int i0 = ti * 128, j0 = tj * 128;
  const int tid = threadIdx.x, lane = tid & 63, wave = tid >> 6;
  const int wr = wave >> 1, wc = wave & 1;
  f32x4 acc[4][4] = {};
  for (int k0 = 0; k0 < DIM; k0 += 64) {
    __syncthreads();
#pragma unroll
    for (int it = 0; it < 8; ++it) {
      const int idx = tid + it * 256;
      const int r = idx >> 4, c4 = idx & 15;
      f32x4 va = *(const f32x4*)(X + (size_t)(i0 + r) * DIM + k0 + c4 * 4);
      f32x4 vb = *(const f32x4*)(X + (size_t)(j0 + r) * DIM + k0 + c4 * 4);
      bf16x4 ha, hb;
      ha[0] = (__bf16)va.x; ha[1] = (__bf16)va.y; ha[2] = (__bf16)va.z; ha[3] = (__bf16)va.w;
      hb[0] = (__bf16)vb.x; hb[1] = (__bf16)vb.y; hb[2] = (__bf16)vb.z; hb[3] = (__bf16)vb.w;
      int off = (r * 128 + c4 * 8) ^ ((r & 7) << 4);
      *(bf16x4*)(sA + off) = ha;
      *(bf16x4*)(sB + off) = hb;
    }
    __syncthreads();
#pragma unroll
    for (int ks = 0; ks < 2; ++ks) {
      bf16x8 af[4], bfr[4];
#pragma unroll
      for (int m = 0; m < 4; ++m) {
        const int ra = wr * 64 + m * 16 + (lane & 15);
        af[m]  = *(const bf16x8*)(sA + ((ra * 128 + ks * 64 + (lane >> 4) * 16) ^ ((ra & 7) << 4)));
        const int rb2 = wc * 64 + m * 16 + (lane & 15);
        bfr[m] = *(const bf16x8*)(sB + ((rb2 * 128 + ks * 64 + (lane >> 4) * 16) ^ ((rb2 & 7) << 4)));
      }
#pragma unroll
      for (int m = 0; m < 4; ++m)
#pragma unroll
        for (int n = 0; n < 4; ++n)
          acc[m][n] = __builtin_amdgcn_mfma_f32_16x16x32_bf16(af[m], bfr[n], acc[m][n], 0, 0, 0);
    }
  }
  const int cg = lane >> 4, cl = lane & 15;
  float sqj[4], colmin[4];
#pragma unroll
  for (int n = 0; n < 4; ++n) { sqj[n] = sq[j0 + wc * 64 + n * 16 + cl]; colmin[n] = INFINITY; }
#pragma unroll
  for (int m = 0; m < 4; ++m) {
#pragma unroll
    for (int r = 0; r < 4; ++r) {
      const int gi = i0 + wr * 64 + m * 16 + cg * 4 + r;
      const float si = sq[gi];
      float rowmin = INFINITY;
#pragma unroll
      for (int n = 0; n < 4; ++n) {
        const int gj = j0 + wc * 64 + n * 16 + cl;
        float d2 = si + sqj[n] - 2.0f * acc[m][n][r];
        d2 = fmaxf(d2, 0.0f);
        if (gi == gj) d2 = INFINITY;
        rowmin = fminf(rowmin, d2);
        colmin[n] = fminf(colmin[n], d2);
      }
      rowmin = fminf(rowmin, __shfl_xor(rowmin, 1, 64));
      rowmin = fminf(rowmin, __shfl_xor(rowmin, 2, 64));
      rowmin = fminf(rowmin, __shfl_xor(rowmin, 4, 64));
      rowmin = fminf(rowmin, __shfl_xor(rowmin, 8, 64));
      if (cl == 0) atomicMin(minbits + gi, __float_as_uint(rowmin));
    }
  }
  if (ti != tj) {
#pragma unroll
    for (int n = 0; n < 4; ++n) {
      float cm = colmin[n];
      cm = fminf(cm, __shfl_xor(cm, 16, 64));
      cm = fminf(cm, __shfl_xor(cm, 32, 64));
      if (cg == 0) atomicMin(minbits + j0 + wc * 64 + n * 16 + cl, __float_as_uint(cm));
    }
  }
}

// ---------------------------------------------------------------------------
// Final: loss = -mean(log(sqrt(min_d2) + eps)), single block
// ---------------------------------------------------------------------------
__global__ __launch_bounds__(1024) void koleo_final(const unsigned int* __restrict__ minbits,
                                                    float* __restrict__ out) {
  __shared__ float wsum[16];
  float s = 0.f;
  for (int i = threadIdx.x; i < NROWS; i += 1024) {
    float d2 = __uint_as_float(minbits[i]);
    s += logf(sqrtf(d2) + 1e-8f);
  }
#pragma unroll
  for (int m = 32; m >= 1; m >>= 1) s += __shfl_xor(s, m, 64);
  const int wv = threadIdx.x >> 6, ln = threadIdx.x & 63;
  if (ln == 0) wsum[wv] = s;
  __syncthreads();
  if (wv == 0) {
    float t = (ln < 16) ? wsum[ln] : 0.f;
#pragma unroll
    for (int m = 8; m >= 1; m >>= 1) t += __shfl_xor(t, m, 64);
    if (ln == 0) out[0] = -t / (float)NROWS;
  }
}

// ---------------------------------------------------------------------------
extern "C" void kernel_launch(void* const* d_in, const int* in_sizes, int n_in,
                              void* d_out, int out_size, void* d_ws, size_t ws_size,
                              hipStream_t stream) {
  const float* X = (const float*)d_in[0];
  float* out = (float*)d_out;
  unsigned int* minbits = (unsigned int*)d_ws;                       // 32 KB
  float* sq = (float*)((char*)d_ws + NROWS * sizeof(unsigned int));  // 32 KB
  char* xbf = (char*)d_ws + 65536;                                   // 12.58 MB

  const size_t need = 65536 + (size_t)NT128 * NKB * CHUNK;
  if (ws_size >= need) {
    koleo_convert<<<NROWS / 4, 256, 0, stream>>>(X, sq, minbits, xbf);
    koleo_tile2<<<NTILES, 256, 65536, stream>>>(xbf, sq, minbits);
  } else {
    koleo_prep_fb<<<NROWS / 4, 256, 0, stream>>>(X, sq, minbits);
    koleo_tile_fb<<<NTILES, 256, 0, stream>>>(X, sq, minbits);
  }
  koleo_final<<<1, 1024, 0, stream>>>(minbits, out);
}